// Round 4
// baseline (1588.339 us; speedup 1.0000x reference)
//
#include <hip/hip_runtime.h>

typedef unsigned short u16;

#define B_ 2
#define N_ 16
#define T_ 512
#define D_ 512
#define H_ 8
#define DH_ 64
#define HALF_ 32
#define FF_ 828
#define DC_ 512
#define LN_EPS 1e-5f
#define PR_EPS 1e-8f
#define NEG_INF (-3.0e38f)

__device__ __forceinline__ float b2f(u16 u) { return __uint_as_float(((unsigned)u) << 16); }
__device__ __forceinline__ u16 f2b(float f) {
  unsigned x = __float_as_uint(f);
  return (u16)((x + 0x7fffu + ((x >> 16) & 1u)) >> 16);
}
__device__ __forceinline__ float gelu_exact(float z) {
  return 0.5f * z * (1.f + erff(z * 0.70710678118654752f));
}

// ---------------- LayerNorm (+ optional gate) ----------------
// one block per (b,n,t); 256 threads, 2 elements each. f32 src, bf16 out.
__global__ __launch_bounds__(256) void ln_gate_kernel(
    const float* __restrict__ xsrc,
    const float* __restrict__ gate_w, const float* __restrict__ gate_b,
    const float* __restrict__ lng, const float* __restrict__ lnb,
    float* __restrict__ gate_out, u16* __restrict__ h_out, int do_gate) {
  __shared__ float red[256];
  int bnt = blockIdx.x;
  int n = (bnt / T_) % N_;
  int tid = threadIdx.x;
  const float* xr = xsrc + (size_t)bnt * D_;
  float x0 = xr[tid], x1 = xr[tid + 256];
  red[tid] = x0 + x1; __syncthreads();
  for (int s = 128; s > 0; s >>= 1) { if (tid < s) red[tid] += red[tid + s]; __syncthreads(); }
  float mu = red[0] * (1.f / D_); __syncthreads();
  float d0 = x0 - mu, d1 = x1 - mu;
  red[tid] = d0 * d0 + d1 * d1; __syncthreads();
  for (int s = 128; s > 0; s >>= 1) { if (tid < s) red[tid] += red[tid + s]; __syncthreads(); }
  float rstd = rsqrtf(red[0] * (1.f / D_) + LN_EPS); __syncthreads();
  if (do_gate) {
    red[tid] = x0 * gate_w[n * D_ + tid] + x1 * gate_w[n * D_ + tid + 256];
    __syncthreads();
    for (int s = 128; s > 0; s >>= 1) { if (tid < s) red[tid] += red[tid + s]; __syncthreads(); }
    if (tid == 0) gate_out[bnt] = (red[0] + gate_b[n] > 0.f) ? 1.f : 0.f;
  }
  size_t o = (size_t)bnt * D_;
  h_out[o + tid]       = f2b(d0 * rstd * lng[n * D_ + tid]       + lnb[n * D_ + tid]);
  h_out[o + tid + 256] = f2b(d1 * rstd * lng[n * D_ + tid + 256] + lnb[n * D_ + tid + 256]);
}

// ---------------- Batched per-node GEMM: Out[bn] = In[bn] (T x Kd) @ W[n] (Kd x E) ----------------
// bf16 activations in, f32 weights, f32 accumulate.
// mode 0: plain->bf16   mode 1: x + Z*gate -> f32 (OutF)   mode 2: gelu(Z+bias)->bf16   mode 3: Z+bias->bf16
__global__ __launch_bounds__(256) void gemm_bn_kernel(
    const u16* __restrict__ In, const float* __restrict__ W, const float* __restrict__ bias,
    u16* __restrict__ Out, float* __restrict__ OutF, int Kd, int E, int mode,
    const float* __restrict__ xres, const float* __restrict__ gate) {
  __shared__ __align__(16) float As[16][68];   // [k][t], padded
  __shared__ __align__(16) float Bs[16][64];   // [k][e]
  int bn = blockIdx.z, n = bn % N_;
  int e0 = blockIdx.x * 64, t0 = blockIdx.y * 64;
  int tid = threadIdx.x;
  int tx = tid & 15, ty = tid >> 4;
  const u16* Inb = In + (size_t)bn * T_ * Kd;
  const float* Wb = W + (size_t)n * Kd * E;
  float acc[4][4] = {};
  for (int k0 = 0; k0 < Kd; k0 += 16) {
    {
      int t = tid >> 2, kq = (tid & 3) * 4;
      int kg = k0 + kq;
      const u16* src = Inb + (size_t)(t0 + t) * Kd;
      float a0 = 0.f, a1 = 0.f, a2 = 0.f, a3 = 0.f;
      if (kg + 3 < Kd) {
        ushort4 a = *(const ushort4*)(src + kg);
        a0 = b2f(a.x); a1 = b2f(a.y); a2 = b2f(a.z); a3 = b2f(a.w);
      } else {
        if (kg + 0 < Kd) a0 = b2f(src[kg + 0]);
        if (kg + 1 < Kd) a1 = b2f(src[kg + 1]);
        if (kg + 2 < Kd) a2 = b2f(src[kg + 2]);
        if (kg + 3 < Kd) a3 = b2f(src[kg + 3]);
      }
      As[kq + 0][t] = a0; As[kq + 1][t] = a1; As[kq + 2][t] = a2; As[kq + 3][t] = a3;
    }
    {
      int kk = tid >> 4, ec = (tid & 15) * 4;
      int e = e0 + ec;
      float bx = 0.f, by = 0.f, bz = 0.f, bw = 0.f;
      if (k0 + kk < Kd) {
        const float* src = Wb + (size_t)(k0 + kk) * E;
        if (e + 3 < E) {
          float4 w4 = *(const float4*)(src + e);
          bx = w4.x; by = w4.y; bz = w4.z; bw = w4.w;
        } else {
          if (e + 0 < E) bx = src[e + 0];
          if (e + 1 < E) by = src[e + 1];
          if (e + 2 < E) bz = src[e + 2];
          if (e + 3 < E) bw = src[e + 3];
        }
      }
      Bs[kk][ec + 0] = bx; Bs[kk][ec + 1] = by; Bs[kk][ec + 2] = bz; Bs[kk][ec + 3] = bw;
    }
    __syncthreads();
    #pragma unroll
    for (int kk = 0; kk < 16; ++kk) {
      float4 a4 = *(const float4*)&As[kk][ty * 4];
      float4 b4 = *(const float4*)&Bs[kk][tx * 4];
      float av[4] = {a4.x, a4.y, a4.z, a4.w};
      float bv[4] = {b4.x, b4.y, b4.z, b4.w};
      #pragma unroll
      for (int i = 0; i < 4; ++i)
        #pragma unroll
        for (int j = 0; j < 4; ++j)
          acc[i][j] = fmaf(av[i], bv[j], acc[i][j]);
    }
    __syncthreads();
  }
  int e = e0 + tx * 4;
  if (e >= E) return;   // E multiple of 4 -> all-or-none per thread column group
  #pragma unroll
  for (int i = 0; i < 4; ++i) {
    int t = t0 + ty * 4 + i;
    size_t o = (size_t)t * E + e;
    float r0 = acc[i][0], r1 = acc[i][1], r2 = acc[i][2], r3 = acc[i][3];
    if (mode == 1) {
      float g = gate[(size_t)bn * T_ + t];
      float4 xv = *(const float4*)(xres + (size_t)bn * T_ * E + o);
      float4 r; r.x = xv.x + r0 * g; r.y = xv.y + r1 * g;
      r.z = xv.z + r2 * g; r.w = xv.w + r3 * g;
      *(float4*)(OutF + (size_t)bn * T_ * E + o) = r;
      continue;
    } else if (mode == 2) {
      r0 = gelu_exact(r0 + bias[(size_t)n * E + e + 0]);
      r1 = gelu_exact(r1 + bias[(size_t)n * E + e + 1]);
      r2 = gelu_exact(r2 + bias[(size_t)n * E + e + 2]);
      r3 = gelu_exact(r3 + bias[(size_t)n * E + e + 3]);
    } else if (mode == 3) {
      r0 += bias[(size_t)n * E + e + 0]; r1 += bias[(size_t)n * E + e + 1];
      r2 += bias[(size_t)n * E + e + 2]; r3 += bias[(size_t)n * E + e + 3];
    }
    ushort4 r; r.x = f2b(r0); r.y = f2b(r1); r.z = f2b(r2); r.w = f2b(r3);
    *(ushort4*)(Out + (size_t)bn * T_ * E + o) = r;
  }
}

// ---------------- in-place rotation + gate on Q and K (bf16) ----------------
__global__ __launch_bounds__(256) void rot_gate_kernel(
    u16* __restrict__ q, u16* __restrict__ k,
    const float* __restrict__ phase, const float* __restrict__ gate) {
  long long i = (long long)blockIdx.x * 256 + threadIdx.x;   // B*N*T*H*HALF threads
  int c = (int)(i & 31);
  int h = (int)((i >> 5) & 7);
  int t = (int)((i >> 8) & 511);
  int bn = (int)(i >> 17);
  int n = bn & (N_ - 1);
  float a = phase[n * H_ + h];
  float ca = cosf(a), sa = sinf(a);
  float g = gate[(size_t)bn * T_ + t];
  size_t base = ((size_t)bn * T_ + t) * D_ + h * DH_;
  float qr = b2f(q[base + c]), qi = b2f(q[base + c + HALF_]);
  q[base + c]         = f2b((qr * ca - qi * sa) * g);
  q[base + c + HALF_] = f2b((qr * sa + qi * ca) * g);
  float kr = b2f(k[base + c]), ki = b2f(k[base + c + HALF_]);
  k[base + c]         = f2b((kr * ca - ki * sa) * g);
  k[base + c + HALF_] = f2b((kr * sa + ki * ca) * g);
}

// ---------------- flash attention: 64 queries / block, K-chunks of 64 ----------------
#define AP 76
__global__ __launch_bounds__(256) void attn_kernel(
    const u16* __restrict__ Q, const u16* __restrict__ K, const u16* __restrict__ V,
    u16* __restrict__ O) {
  __shared__ __align__(16) float Qs[64 * AP];
  __shared__ __align__(16) float KPs[64 * AP];  // K chunk, reused for P
  __shared__ __align__(16) float Vs[64 * AP];
  int qt = blockIdx.x, h = blockIdx.y, bn = blockIdx.z;
  int tid = threadIdx.x, tx = tid & 15, ty = tid >> 4;
  int t0 = qt * 64;
  size_t rowbase = (size_t)bn * T_ * D_ + (size_t)h * DH_;
  {
    int col = tx * 4;
    #pragma unroll
    for (int r = 0; r < 4; ++r) {
      int qq = ty + r * 16;
      ushort4 v4 = *(const ushort4*)(Q + rowbase + (size_t)(t0 + qq) * D_ + col);
      float4 sv; sv.x = b2f(v4.x) * 0.125f; sv.y = b2f(v4.y) * 0.125f;
      sv.z = b2f(v4.z) * 0.125f; sv.w = b2f(v4.w) * 0.125f;
      *(float4*)&Qs[qq * AP + col] = sv;
    }
  }
  float m[4], l[4], o[4][4];
  #pragma unroll
  for (int i = 0; i < 4; ++i) {
    m[i] = NEG_INF; l[i] = 0.f;
    #pragma unroll
    for (int c = 0; c < 4; ++c) o[i][c] = 0.f;
  }
  int q0 = ty * 4, j0 = tx * 4, d0 = tx * 4;
  for (int sc = 0; sc < 8; ++sc) {
    int s0 = sc * 64;
    {
      int col = tx * 4;
      #pragma unroll
      for (int r = 0; r < 4; ++r) {
        int jj = ty + r * 16;
        ushort4 kv = *(const ushort4*)(K + rowbase + (size_t)(s0 + jj) * D_ + col);
        ushort4 vv = *(const ushort4*)(V + rowbase + (size_t)(s0 + jj) * D_ + col);
        float4 kf; kf.x = b2f(kv.x); kf.y = b2f(kv.y); kf.z = b2f(kv.z); kf.w = b2f(kv.w);
        float4 vf; vf.x = b2f(vv.x); vf.y = b2f(vv.y); vf.z = b2f(vv.z); vf.w = b2f(vv.w);
        *(float4*)&KPs[jj * AP + col] = kf;
        *(float4*)&Vs[jj * AP + col]  = vf;
      }
    }
    __syncthreads();
    float s[4][4] = {};
    #pragma unroll 4
    for (int d4 = 0; d4 < 64; d4 += 4) {
      float4 qv[4], kv[4];
      #pragma unroll
      for (int i = 0; i < 4; ++i) qv[i] = *(const float4*)&Qs[(q0 + i) * AP + d4];
      #pragma unroll
      for (int j = 0; j < 4; ++j) kv[j] = *(const float4*)&KPs[(j0 + j) * AP + d4];
      #pragma unroll
      for (int i = 0; i < 4; ++i)
        #pragma unroll
        for (int j = 0; j < 4; ++j)
          s[i][j] += qv[i].x * kv[j].x + qv[i].y * kv[j].y + qv[i].z * kv[j].z + qv[i].w * kv[j].w;
    }
    __syncthreads();   // all reads of K chunk done; KPs becomes P
    #pragma unroll
    for (int i = 0; i < 4; ++i) {
      float cm = fmaxf(fmaxf(s[i][0], s[i][1]), fmaxf(s[i][2], s[i][3]));
      #pragma unroll
      for (int off = 1; off < 16; off <<= 1) cm = fmaxf(cm, __shfl_xor(cm, off));
      float mn = fmaxf(m[i], cm);
      float al = expf(m[i] - mn);
      float p0 = expf(s[i][0] - mn), p1 = expf(s[i][1] - mn);
      float p2 = expf(s[i][2] - mn), p3 = expf(s[i][3] - mn);
      float rs = p0 + p1 + p2 + p3;
      #pragma unroll
      for (int off = 1; off < 16; off <<= 1) rs += __shfl_xor(rs, off);
      l[i] = l[i] * al + rs;
      m[i] = mn;
      #pragma unroll
      for (int c = 0; c < 4; ++c) o[i][c] *= al;
      float4 pv; pv.x = p0; pv.y = p1; pv.z = p2; pv.w = p3;
      *(float4*)&KPs[(q0 + i) * AP + j0] = pv;
    }
    __syncthreads();
    #pragma unroll 4
    for (int jb = 0; jb < 64; jb += 4) {
      float4 pm[4], vv[4];
      #pragma unroll
      for (int i = 0; i < 4; ++i) pm[i] = *(const float4*)&KPs[(q0 + i) * AP + jb];
      #pragma unroll
      for (int jj = 0; jj < 4; ++jj) vv[jj] = *(const float4*)&Vs[(jb + jj) * AP + d0];
      #pragma unroll
      for (int i = 0; i < 4; ++i) {
        o[i][0] += pm[i].x * vv[0].x + pm[i].y * vv[1].x + pm[i].z * vv[2].x + pm[i].w * vv[3].x;
        o[i][1] += pm[i].x * vv[0].y + pm[i].y * vv[1].y + pm[i].z * vv[2].y + pm[i].w * vv[3].y;
        o[i][2] += pm[i].x * vv[0].z + pm[i].y * vv[1].z + pm[i].z * vv[2].z + pm[i].w * vv[3].z;
        o[i][3] += pm[i].x * vv[0].w + pm[i].y * vv[1].w + pm[i].z * vv[2].w + pm[i].w * vv[3].w;
      }
    }
    __syncthreads();
  }
  #pragma unroll
  for (int i = 0; i < 4; ++i) {
    float inv = 1.f / l[i];
    ushort4 r;
    r.x = f2b(o[i][0] * inv); r.y = f2b(o[i][1] * inv);
    r.z = f2b(o[i][2] * inv); r.w = f2b(o[i][3] * inv);
    *(ushort4*)(O + rowbase + (size_t)(t0 + q0 + i) * D_ + d0) = r;
  }
}

// ---------------- small bn-level kernels ----------------
__global__ __launch_bounds__(256) void pool_kernel(const float* __restrict__ x2, float* __restrict__ cp) {
  int bid = blockIdx.x;            // B*N*2
  int bn = bid >> 1;
  int d = (bid & 1) * 256 + threadIdx.x;
  const float* base = x2 + (size_t)bn * T_ * D_ + d;
  float s = 0.f;
  for (int t = 0; t < T_; ++t) s += base[(size_t)t * D_];
  cp[(size_t)bn * D_ + d] = s * (1.f / T_);
}

__global__ __launch_bounds__(256) void commit_center_kernel(
    const float* __restrict__ cp, const float* __restrict__ commit_w, const float* __restrict__ commit_b,
    const float* __restrict__ center_w, const float* __restrict__ center_b,
    float* __restrict__ commit, float* __restrict__ center) {
  __shared__ float cps[512];
  __shared__ float red[256];
  int bn = blockIdx.x, n = bn % N_, tid = threadIdx.x;
  cps[tid] = cp[(size_t)bn * D_ + tid];
  cps[tid + 256] = cp[(size_t)bn * D_ + tid + 256];
  __syncthreads();
  red[tid] = cps[tid] * commit_w[n * D_ + tid] + cps[tid + 256] * commit_w[n * D_ + tid + 256];
  __syncthreads();
  for (int s = 128; s > 0; s >>= 1) { if (tid < s) red[tid] += red[tid + s]; __syncthreads(); }
  if (tid == 0) commit[bn] = 1.f / (1.f + expf(-(red[0] + commit_b[n])));
  #pragma unroll
  for (int eo = 0; eo < 2; ++eo) {
    int e = eo * 256 + tid;
    float acc = center_b[(size_t)n * DC_ + e];
    for (int d = 0; d < D_; ++d) acc = fmaf(cps[d], center_w[((size_t)n * D_ + d) * DC_ + e], acc);
    center[(size_t)bn * DC_ + e] = tanhf(acc);
  }
}

__global__ __launch_bounds__(256) void matvec_kernel(
    const float* __restrict__ inp, const float* __restrict__ Wm, float* __restrict__ outp) {
  __shared__ float s[512];
  int bn = blockIdx.x, tid = threadIdx.x;
  s[tid] = inp[(size_t)bn * D_ + tid];
  s[tid + 256] = inp[(size_t)bn * D_ + tid + 256];
  __syncthreads();
  #pragma unroll
  for (int eo = 0; eo < 2; ++eo) {
    int e = eo * 256 + tid;
    float acc = 0.f;
    for (int d = 0; d < D_; ++d) acc = fmaf(s[d], Wm[(size_t)d * D_ + e], acc);
    outp[(size_t)bn * D_ + e] = acc;
  }
}

// unit phase vectors: u = (re+eps)/r, v = (im+eps)/r  (== cos/sin of atan2)
__global__ __launch_bounds__(256) void uv_kernel(
    const float* __restrict__ hres, float* __restrict__ u, float* __restrict__ v) {
  int i = blockIdx.x * 256 + threadIdx.x;   // B*N*256
  float xr = hres[2 * i] + PR_EPS;
  float yi = hres[2 * i + 1] + PR_EPS;
  float r = sqrtf(xr * xr + yi * yi);
  u[i] = xr / r; v[i] = yi / r;
}

__global__ __launch_bounds__(256) void racc_kernel(
    const float* __restrict__ u, const float* __restrict__ v, float* __restrict__ ra) {
  int b = blockIdx.x, tid = threadIdx.x;
  int mm = tid >> 4, nn = tid & 15;
  const float* ub = u + (size_t)b * N_ * 256;
  const float* vb = v + (size_t)b * N_ * 256;
  float acc = 0.f;
  for (int p = 0; p < 256; ++p)
    acc += ub[mm * 256 + p] * ub[nn * 256 + p] + vb[mm * 256 + p] * vb[nn * 256 + p];
  ra[(size_t)b * N_ * N_ + mm * N_ + nn] = acc * (1.f / 256.f);
}

__global__ __launch_bounds__(256) void recv_kernel(
    const float* __restrict__ ra, const float* __restrict__ commit,
    const float* __restrict__ hres, const float* __restrict__ cond, float* __restrict__ recv) {
  int bn = blockIdx.x, b = bn / N_, mm = bn % N_, tid = threadIdx.x;
  float c = cond[0];
  #pragma unroll
  for (int eo = 0; eo < 2; ++eo) {
    int d = eo * 256 + tid;
    float acc = 0.f;
    for (int nn = 0; nn < N_; ++nn)
      acc += ra[(size_t)b * N_ * N_ + mm * N_ + nn] * commit[b * N_ + nn] *
             hres[((size_t)b * N_ + nn) * D_ + d];
    recv[(size_t)bn * D_ + d] = c * acc;
  }
}

__global__ __launch_bounds__(256) void final_kernel(
    const float* __restrict__ x2, const float* __restrict__ commit,
    const float* __restrict__ gate, const u16* __restrict__ ff,
    const float* __restrict__ fs, float* __restrict__ out) {
  long long i4 = (long long)blockIdx.x * 256 + threadIdx.x;
  long long base = i4 * 4;
  int d = (int)(base & (D_ - 1));
  int t = (int)((base >> 9) & (T_ - 1));
  int bn = (int)(base >> 18);
  float cg = commit[bn] * gate[(size_t)bn * T_ + t];
  float4 xv = *(const float4*)(x2 + base);
  ushort4 fv = *(const ushort4*)(ff + base);
  float4 sv = *(const float4*)(fs + (size_t)bn * D_ + d);
  float4 r;
  r.x = xv.x + cg * b2f(fv.x) + sv.x;
  r.y = xv.y + cg * b2f(fv.y) + sv.y;
  r.z = xv.z + cg * b2f(fv.z) + sv.z;
  r.w = xv.w + cg * b2f(fv.w) + sv.w;
  *(float4*)(out + base) = r;
}

extern "C" void kernel_launch(void* const* d_in, const int* in_sizes, int n_in,
                              void* d_out, int out_size, void* d_ws, size_t ws_size,
                              hipStream_t stream) {
  (void)in_sizes; (void)n_in; (void)out_size; (void)ws_size;
  const float* x          = (const float*)d_in[0];
  const float* gate_w     = (const float*)d_in[1];
  const float* gate_b     = (const float*)d_in[2];
  const float* ln1_g      = (const float*)d_in[3];
  const float* ln1_b      = (const float*)d_in[4];
  const float* wq         = (const float*)d_in[5];
  const float* wk         = (const float*)d_in[6];
  const float* wv         = (const float*)d_in[7];
  const float* wo         = (const float*)d_in[8];
  const float* phase      = (const float*)d_in[9];
  const float* ln2_g      = (const float*)d_in[10];
  const float* ln2_b      = (const float*)d_in[11];
  const float* up_w       = (const float*)d_in[12];
  const float* up_b       = (const float*)d_in[13];
  const float* down_w     = (const float*)d_in[14];
  const float* down_b     = (const float*)d_in[15];
  const float* commit_w   = (const float*)d_in[16];
  const float* commit_b   = (const float*)d_in[17];
  const float* center_w   = (const float*)d_in[18];
  const float* center_b   = (const float*)d_in[19];
  const float* field_in_w = (const float*)d_in[20];
  const float* field_out_w= (const float*)d_in[21];
  const float* cond       = (const float*)d_in[22];

  const long long BNTD = 8388608LL;     // 2*16*512*512
  // workspace layout (bf16 big regions + f32 smalls, total ~64.6 MiB):
  u16* w16 = (u16*)d_ws;
  u16* R0 = w16;               // h -> attnout -> ff
  u16* R1 = w16 + BNTD;        // Q -> h2
  u16* R2 = w16 + 2 * BNTD;    // K -> up[0..)
  u16* R3 = w16 + 3 * BNTD;    // V -> up tail (up spans R2..R2+13565952 < 2*BNTD)
  float* sm   = (float*)(w16 + 4 * BNTD);
  float* gate   = sm;            // 16384
  float* cp     = sm + 16384;    // 16384
  float* center = sm + 2 * 16384;
  float* hres   = sm + 3 * 16384;
  float* uu     = sm + 4 * 16384; // 8192
  float* vv     = uu + 8192;      // 8192
  float* ra     = vv + 8192;      // 512
  float* recvb  = ra + 512;       // 16384
  float* fsig   = recvb + 16384;  // 16384
  float* commit = fsig + 16384;   // 32
  float* x2 = (float*)d_out;      // x2 lives in d_out (f32); final updates it in place

  ln_gate_kernel<<<16384, 256, 0, stream>>>(x, gate_w, gate_b, ln1_g, ln1_b, gate, R0, 1);
  dim3 g8(8, 8, 32);
  gemm_bn_kernel<<<g8, 256, 0, stream>>>(R0, wq, nullptr, R1, nullptr, 512, 512, 0, nullptr, nullptr);
  gemm_bn_kernel<<<g8, 256, 0, stream>>>(R0, wk, nullptr, R2, nullptr, 512, 512, 0, nullptr, nullptr);
  gemm_bn_kernel<<<g8, 256, 0, stream>>>(R0, wv, nullptr, R3, nullptr, 512, 512, 0, nullptr, nullptr);
  rot_gate_kernel<<<16384, 256, 0, stream>>>(R1, R2, phase, gate);
  attn_kernel<<<dim3(8, 8, 32), 256, 0, stream>>>(R1, R2, R3, R0);
  gemm_bn_kernel<<<g8, 256, 0, stream>>>(R0, wo, nullptr, nullptr, x2, 512, 512, 1, x, gate);
  ln_gate_kernel<<<16384, 256, 0, stream>>>(x2, nullptr, nullptr, ln2_g, ln2_b, nullptr, R1, 0);
  gemm_bn_kernel<<<dim3(13, 8, 32), 256, 0, stream>>>(R1, up_w, up_b, R2, nullptr, 512, 828, 2, nullptr, nullptr);
  gemm_bn_kernel<<<g8, 256, 0, stream>>>(R2, down_w, down_b, R0, nullptr, 828, 512, 3, nullptr, nullptr);
  pool_kernel<<<64, 256, 0, stream>>>(x2, cp);
  commit_center_kernel<<<32, 256, 0, stream>>>(cp, commit_w, commit_b, center_w, center_b, commit, center);
  matvec_kernel<<<32, 256, 0, stream>>>(center, field_in_w, hres);
  uv_kernel<<<32, 256, 0, stream>>>(hres, uu, vv);
  racc_kernel<<<2, 256, 0, stream>>>(uu, vv, ra);
  recv_kernel<<<32, 256, 0, stream>>>(ra, commit, hres, cond, recvb);
  matvec_kernel<<<32, 256, 0, stream>>>(recvb, field_out_w, fsig);
  final_kernel<<<8192, 256, 0, stream>>>(x2, commit, gate, R0, fsig, x2);
}

// Round 5
// 1172.779 us; speedup vs baseline: 1.3543x; 1.3543x over previous
//
#include <hip/hip_runtime.h>

typedef unsigned short u16;
typedef __attribute__((ext_vector_type(8))) short short8;
typedef __attribute__((ext_vector_type(4))) float f32x4;

#define B_ 2
#define N_ 16
#define T_ 512
#define D_ 512
#define H_ 8
#define DH_ 64
#define HALF_ 32
#define FF_ 828
#define DC_ 512
#define LN_EPS 1e-5f
#define PR_EPS 1e-8f
#define NEG_INF (-3.0e38f)

__device__ __forceinline__ float b2f(u16 u) { return __uint_as_float(((unsigned)u) << 16); }
__device__ __forceinline__ u16 f2b(float f) {
  unsigned x = __float_as_uint(f);
  return (u16)((x + 0x7fffu + ((x >> 16) & 1u)) >> 16);
}
__device__ __forceinline__ float gelu_exact(float z) {
  return 0.5f * z * (1.f + erff(z * 0.70710678118654752f));
}

// ---------------- LayerNorm (+ optional gate) ----------------
__global__ __launch_bounds__(256) void ln_gate_kernel(
    const float* __restrict__ xsrc,
    const float* __restrict__ gate_w, const float* __restrict__ gate_b,
    const float* __restrict__ lng, const float* __restrict__ lnb,
    float* __restrict__ gate_out, u16* __restrict__ h_out, int do_gate) {
  __shared__ float red[256];
  int bnt = blockIdx.x;
  int n = (bnt / T_) % N_;
  int tid = threadIdx.x;
  const float* xr = xsrc + (size_t)bnt * D_;
  float x0 = xr[tid], x1 = xr[tid + 256];
  red[tid] = x0 + x1; __syncthreads();
  for (int s = 128; s > 0; s >>= 1) { if (tid < s) red[tid] += red[tid + s]; __syncthreads(); }
  float mu = red[0] * (1.f / D_); __syncthreads();
  float d0 = x0 - mu, d1 = x1 - mu;
  red[tid] = d0 * d0 + d1 * d1; __syncthreads();
  for (int s = 128; s > 0; s >>= 1) { if (tid < s) red[tid] += red[tid + s]; __syncthreads(); }
  float rstd = rsqrtf(red[0] * (1.f / D_) + LN_EPS); __syncthreads();
  if (do_gate) {
    red[tid] = x0 * gate_w[n * D_ + tid] + x1 * gate_w[n * D_ + tid + 256];
    __syncthreads();
    for (int s = 128; s > 0; s >>= 1) { if (tid < s) red[tid] += red[tid + s]; __syncthreads(); }
    if (tid == 0) gate_out[bnt] = (red[0] + gate_b[n] > 0.f) ? 1.f : 0.f;
  }
  size_t o = (size_t)bnt * D_;
  h_out[o + tid]       = f2b(d0 * rstd * lng[n * D_ + tid]       + lnb[n * D_ + tid]);
  h_out[o + tid + 256] = f2b(d1 * rstd * lng[n * D_ + tid + 256] + lnb[n * D_ + tid + 256]);
}

// ---------------- MFMA batched per-node GEMM ----------------
// Out[bn] (T x E) = In[bn] (T x Kd, bf16) @ W[n] (Kd x E, f32 -> bf16 in staging)
// 128x128 tile, 4 waves, each wave 64x64 via 4x4 grid of mfma_f32_16x16x32_bf16.
// mode 0: ->bf16  1: x + Z*gate -> f32  2: gelu(Z+bias)->bf16  3: Z+bias->bf16
#define BM 128
#define BN 128
#define BK 32
#define LST 40   // LDS row stride in bf16 elems (32 + 8 pad; keeps 16B align, spreads banks)
__global__ __launch_bounds__(256) void gemm_mfma_kernel(
    const u16* __restrict__ In,
    const float* __restrict__ W0, const float* __restrict__ W1, const float* __restrict__ W2,
    u16* __restrict__ O0, u16* __restrict__ O1, u16* __restrict__ O2,
    float* __restrict__ OutF,
    int Kd, int E, int mode,
    const float* __restrict__ bias,
    const float* __restrict__ xres, const float* __restrict__ gate) {
  __shared__ u16 As[BM * LST];
  __shared__ u16 Bs[BN * LST];
  int z = blockIdx.z;
  int bn = z & 31, proj = z >> 5;
  int n = bn & (N_ - 1);
  const float* W = (proj == 0) ? W0 : ((proj == 1) ? W1 : W2);
  u16* Out = (proj == 0) ? O0 : ((proj == 1) ? O1 : O2);
  int e0 = blockIdx.x * BN, t0 = blockIdx.y * BM;
  int tid = threadIdx.x;
  int lane = tid & 63, wave = tid >> 6;
  int m_off = (wave & 1) * 64, n_off = (wave >> 1) * 64;
  int ml = lane & 15, quad = lane >> 4;
  const u16* Inb = In + (size_t)bn * T_ * Kd;
  const float* Wb = W + (size_t)n * Kd * E;

  f32x4 acc[4][4] = {};

  int ksteps = (Kd + BK - 1) / BK;
  for (int ks = 0; ks < ksteps; ++ks) {
    int k0 = ks * BK;
    // ---- stage A: BM x BK bf16 (each thread: 2 slots of 8 elems) ----
    #pragma unroll
    for (int it = 0; it < 2; ++it) {
      int slot = tid * 2 + it;       // 0..511
      int r = slot >> 2;             // row 0..127
      int q = slot & 3;              // k-quarter
      int kg = k0 + q * 8;
      const u16* src = Inb + (size_t)(t0 + r) * Kd + kg;
      u16* dst = &As[r * LST + q * 8];
      if (kg + 8 <= Kd) {
        *(ushort4*)(dst)     = *(const ushort4*)(src);
        *(ushort4*)(dst + 4) = *(const ushort4*)(src + 4);
      } else {
        #pragma unroll
        for (int xx = 0; xx < 8; ++xx) dst[xx] = (kg + xx < Kd) ? src[xx] : (u16)0;
      }
    }
    // ---- stage B transposed: Bs[e_local][k_local], f32 -> bf16 ----
    {
      int kk = tid & 31;             // k_local
      int eb = (tid >> 5) * 16;      // e_local base
      int kg = k0 + kk;
      #pragma unroll
      for (int it = 0; it < 4; ++it) {
        int e = eb + it * 4;
        int eg = e0 + e;
        float4 w4 = {0.f, 0.f, 0.f, 0.f};
        if (kg < Kd && eg < E) w4 = *(const float4*)(Wb + (size_t)kg * E + eg);
        Bs[(e + 0) * LST + kk] = f2b(w4.x);
        Bs[(e + 1) * LST + kk] = f2b(w4.y);
        Bs[(e + 2) * LST + kk] = f2b(w4.z);
        Bs[(e + 3) * LST + kk] = f2b(w4.w);
      }
    }
    __syncthreads();
    // ---- MFMA: 4x4 tiles of 16x16x32 per wave ----
    short8 a[4], b[4];
    #pragma unroll
    for (int i = 0; i < 4; ++i)
      a[i] = *(const short8*)&As[(m_off + i * 16 + ml) * LST + quad * 8];
    #pragma unroll
    for (int j = 0; j < 4; ++j)
      b[j] = *(const short8*)&Bs[(n_off + j * 16 + ml) * LST + quad * 8];
    #pragma unroll
    for (int i = 0; i < 4; ++i)
      #pragma unroll
      for (int j = 0; j < 4; ++j)
        acc[i][j] = __builtin_amdgcn_mfma_f32_16x16x32_bf16(a[i], b[j], acc[i][j], 0, 0, 0);
    __syncthreads();
  }

  // ---- epilogue: C/D layout col=lane&15, row=quad*4+reg ----
  #pragma unroll
  for (int j = 0; j < 4; ++j) {
    int eg = e0 + n_off + j * 16 + ml;
    if (eg >= E) continue;
    #pragma unroll
    for (int i = 0; i < 4; ++i) {
      #pragma unroll
      for (int r = 0; r < 4; ++r) {
        int tg = t0 + m_off + i * 16 + quad * 4 + r;
        float v = acc[i][j][r];
        size_t o = (size_t)bn * T_ * E + (size_t)tg * E + eg;
        if (mode == 0) {
          Out[o] = f2b(v);
        } else if (mode == 1) {
          float g = gate[(size_t)bn * T_ + tg];
          OutF[o] = xres[o] + v * g;
        } else if (mode == 2) {
          Out[o] = f2b(gelu_exact(v + bias[(size_t)n * E + eg]));
        } else {
          Out[o] = f2b(v + bias[(size_t)n * E + eg]);
        }
      }
    }
  }
}

// ---------------- in-place rotation + gate on Q and K (bf16) ----------------
__global__ __launch_bounds__(256) void rot_gate_kernel(
    u16* __restrict__ q, u16* __restrict__ k,
    const float* __restrict__ phase, const float* __restrict__ gate) {
  long long i = (long long)blockIdx.x * 256 + threadIdx.x;
  int c = (int)(i & 31);
  int h = (int)((i >> 5) & 7);
  int t = (int)((i >> 8) & 511);
  int bn = (int)(i >> 17);
  int n = bn & (N_ - 1);
  float a = phase[n * H_ + h];
  float ca = cosf(a), sa = sinf(a);
  float g = gate[(size_t)bn * T_ + t];
  size_t base = ((size_t)bn * T_ + t) * D_ + h * DH_;
  float qr = b2f(q[base + c]), qi = b2f(q[base + c + HALF_]);
  q[base + c]         = f2b((qr * ca - qi * sa) * g);
  q[base + c + HALF_] = f2b((qr * sa + qi * ca) * g);
  float kr = b2f(k[base + c]), ki = b2f(k[base + c + HALF_]);
  k[base + c]         = f2b((kr * ca - ki * sa) * g);
  k[base + c + HALF_] = f2b((kr * sa + ki * ca) * g);
}

// ---------------- flash attention: 64 queries / block, K-chunks of 64 ----------------
#define AP 76
__global__ __launch_bounds__(256) void attn_kernel(
    const u16* __restrict__ Q, const u16* __restrict__ K, const u16* __restrict__ V,
    u16* __restrict__ O) {
  __shared__ __align__(16) float Qs[64 * AP];
  __shared__ __align__(16) float KPs[64 * AP];
  __shared__ __align__(16) float Vs[64 * AP];
  int qt = blockIdx.x, h = blockIdx.y, bn = blockIdx.z;
  int tid = threadIdx.x, tx = tid & 15, ty = tid >> 4;
  int t0 = qt * 64;
  size_t rowbase = (size_t)bn * T_ * D_ + (size_t)h * DH_;
  {
    int col = tx * 4;
    #pragma unroll
    for (int r = 0; r < 4; ++r) {
      int qq = ty + r * 16;
      ushort4 v4 = *(const ushort4*)(Q + rowbase + (size_t)(t0 + qq) * D_ + col);
      float4 sv; sv.x = b2f(v4.x) * 0.125f; sv.y = b2f(v4.y) * 0.125f;
      sv.z = b2f(v4.z) * 0.125f; sv.w = b2f(v4.w) * 0.125f;
      *(float4*)&Qs[qq * AP + col] = sv;
    }
  }
  float m[4], l[4], o[4][4];
  #pragma unroll
  for (int i = 0; i < 4; ++i) {
    m[i] = NEG_INF; l[i] = 0.f;
    #pragma unroll
    for (int c = 0; c < 4; ++c) o[i][c] = 0.f;
  }
  int q0 = ty * 4, j0 = tx * 4, d0 = tx * 4;
  for (int sc = 0; sc < 8; ++sc) {
    int s0 = sc * 64;
    {
      int col = tx * 4;
      #pragma unroll
      for (int r = 0; r < 4; ++r) {
        int jj = ty + r * 16;
        ushort4 kv = *(const ushort4*)(K + rowbase + (size_t)(s0 + jj) * D_ + col);
        ushort4 vv = *(const ushort4*)(V + rowbase + (size_t)(s0 + jj) * D_ + col);
        float4 kf; kf.x = b2f(kv.x); kf.y = b2f(kv.y); kf.z = b2f(kv.z); kf.w = b2f(kv.w);
        float4 vf; vf.x = b2f(vv.x); vf.y = b2f(vv.y); vf.z = b2f(vv.z); vf.w = b2f(vv.w);
        *(float4*)&KPs[jj * AP + col] = kf;
        *(float4*)&Vs[jj * AP + col]  = vf;
      }
    }
    __syncthreads();
    float s[4][4] = {};
    #pragma unroll 4
    for (int d4 = 0; d4 < 64; d4 += 4) {
      float4 qv[4], kv[4];
      #pragma unroll
      for (int i = 0; i < 4; ++i) qv[i] = *(const float4*)&Qs[(q0 + i) * AP + d4];
      #pragma unroll
      for (int j = 0; j < 4; ++j) kv[j] = *(const float4*)&KPs[(j0 + j) * AP + d4];
      #pragma unroll
      for (int i = 0; i < 4; ++i)
        #pragma unroll
        for (int j = 0; j < 4; ++j)
          s[i][j] += qv[i].x * kv[j].x + qv[i].y * kv[j].y + qv[i].z * kv[j].z + qv[i].w * kv[j].w;
    }
    __syncthreads();
    #pragma unroll
    for (int i = 0; i < 4; ++i) {
      float cm = fmaxf(fmaxf(s[i][0], s[i][1]), fmaxf(s[i][2], s[i][3]));
      #pragma unroll
      for (int off = 1; off < 16; off <<= 1) cm = fmaxf(cm, __shfl_xor(cm, off));
      float mn = fmaxf(m[i], cm);
      float al = expf(m[i] - mn);
      float p0 = expf(s[i][0] - mn), p1 = expf(s[i][1] - mn);
      float p2 = expf(s[i][2] - mn), p3 = expf(s[i][3] - mn);
      float rs = p0 + p1 + p2 + p3;
      #pragma unroll
      for (int off = 1; off < 16; off <<= 1) rs += __shfl_xor(rs, off);
      l[i] = l[i] * al + rs;
      m[i] = mn;
      #pragma unroll
      for (int c = 0; c < 4; ++c) o[i][c] *= al;
      float4 pv; pv.x = p0; pv.y = p1; pv.z = p2; pv.w = p3;
      *(float4*)&KPs[(q0 + i) * AP + j0] = pv;
    }
    __syncthreads();
    #pragma unroll 4
    for (int jb = 0; jb < 64; jb += 4) {
      float4 pm[4], vv[4];
      #pragma unroll
      for (int i = 0; i < 4; ++i) pm[i] = *(const float4*)&KPs[(q0 + i) * AP + jb];
      #pragma unroll
      for (int jj = 0; jj < 4; ++jj) vv[jj] = *(const float4*)&Vs[(jb + jj) * AP + d0];
      #pragma unroll
      for (int i = 0; i < 4; ++i) {
        o[i][0] += pm[i].x * vv[0].x + pm[i].y * vv[1].x + pm[i].z * vv[2].x + pm[i].w * vv[3].x;
        o[i][1] += pm[i].x * vv[0].y + pm[i].y * vv[1].y + pm[i].z * vv[2].y + pm[i].w * vv[3].y;
        o[i][2] += pm[i].x * vv[0].z + pm[i].y * vv[1].z + pm[i].z * vv[2].z + pm[i].w * vv[3].z;
        o[i][3] += pm[i].x * vv[0].w + pm[i].y * vv[1].w + pm[i].z * vv[2].w + pm[i].w * vv[3].w;
      }
    }
    __syncthreads();
  }
  #pragma unroll
  for (int i = 0; i < 4; ++i) {
    float inv = 1.f / l[i];
    ushort4 r;
    r.x = f2b(o[i][0] * inv); r.y = f2b(o[i][1] * inv);
    r.z = f2b(o[i][2] * inv); r.w = f2b(o[i][3] * inv);
    *(ushort4*)(O + rowbase + (size_t)(t0 + q0 + i) * D_ + d0) = r;
  }
}

// ---------------- small bn-level kernels ----------------
__global__ __launch_bounds__(256) void pool_kernel(const float* __restrict__ x2, float* __restrict__ cp) {
  int bid = blockIdx.x;
  int bn = bid >> 1;
  int d = (bid & 1) * 256 + threadIdx.x;
  const float* base = x2 + (size_t)bn * T_ * D_ + d;
  float s = 0.f;
  for (int t = 0; t < T_; ++t) s += base[(size_t)t * D_];
  cp[(size_t)bn * D_ + d] = s * (1.f / T_);
}

__global__ __launch_bounds__(256) void commit_center_kernel(
    const float* __restrict__ cp, const float* __restrict__ commit_w, const float* __restrict__ commit_b,
    const float* __restrict__ center_w, const float* __restrict__ center_b,
    float* __restrict__ commit, float* __restrict__ center) {
  __shared__ float cps[512];
  __shared__ float red[256];
  int bn = blockIdx.x, n = bn % N_, tid = threadIdx.x;
  cps[tid] = cp[(size_t)bn * D_ + tid];
  cps[tid + 256] = cp[(size_t)bn * D_ + tid + 256];
  __syncthreads();
  red[tid] = cps[tid] * commit_w[n * D_ + tid] + cps[tid + 256] * commit_w[n * D_ + tid + 256];
  __syncthreads();
  for (int s = 128; s > 0; s >>= 1) { if (tid < s) red[tid] += red[tid + s]; __syncthreads(); }
  if (tid == 0) commit[bn] = 1.f / (1.f + expf(-(red[0] + commit_b[n])));
  #pragma unroll
  for (int eo = 0; eo < 2; ++eo) {
    int e = eo * 256 + tid;
    float acc = center_b[(size_t)n * DC_ + e];
    for (int d = 0; d < D_; ++d) acc = fmaf(cps[d], center_w[((size_t)n * D_ + d) * DC_ + e], acc);
    center[(size_t)bn * DC_ + e] = tanhf(acc);
  }
}

__global__ __launch_bounds__(256) void matvec_kernel(
    const float* __restrict__ inp, const float* __restrict__ Wm, float* __restrict__ outp) {
  __shared__ float s[512];
  int bn = blockIdx.x, tid = threadIdx.x;
  s[tid] = inp[(size_t)bn * D_ + tid];
  s[tid + 256] = inp[(size_t)bn * D_ + tid + 256];
  __syncthreads();
  #pragma unroll
  for (int eo = 0; eo < 2; ++eo) {
    int e = eo * 256 + tid;
    float acc = 0.f;
    for (int d = 0; d < D_; ++d) acc = fmaf(s[d], Wm[(size_t)d * D_ + e], acc);
    outp[(size_t)bn * D_ + e] = acc;
  }
}

__global__ __launch_bounds__(256) void uv_kernel(
    const float* __restrict__ hres, float* __restrict__ u, float* __restrict__ v) {
  int i = blockIdx.x * 256 + threadIdx.x;
  float xr = hres[2 * i] + PR_EPS;
  float yi = hres[2 * i + 1] + PR_EPS;
  float r = sqrtf(xr * xr + yi * yi);
  u[i] = xr / r; v[i] = yi / r;
}

__global__ __launch_bounds__(256) void racc_kernel(
    const float* __restrict__ u, const float* __restrict__ v, float* __restrict__ ra) {
  int b = blockIdx.x, tid = threadIdx.x;
  int mm = tid >> 4, nn = tid & 15;
  const float* ub = u + (size_t)b * N_ * 256;
  const float* vb = v + (size_t)b * N_ * 256;
  float acc = 0.f;
  for (int p = 0; p < 256; ++p)
    acc += ub[mm * 256 + p] * ub[nn * 256 + p] + vb[mm * 256 + p] * vb[nn * 256 + p];
  ra[(size_t)b * N_ * N_ + mm * N_ + nn] = acc * (1.f / 256.f);
}

__global__ __launch_bounds__(256) void recv_kernel(
    const float* __restrict__ ra, const float* __restrict__ commit,
    const float* __restrict__ hres, const float* __restrict__ cond, float* __restrict__ recv) {
  int bn = blockIdx.x, b = bn / N_, mm = bn % N_, tid = threadIdx.x;
  float c = cond[0];
  #pragma unroll
  for (int eo = 0; eo < 2; ++eo) {
    int d = eo * 256 + tid;
    float acc = 0.f;
    for (int nn = 0; nn < N_; ++nn)
      acc += ra[(size_t)b * N_ * N_ + mm * N_ + nn] * commit[b * N_ + nn] *
             hres[((size_t)b * N_ + nn) * D_ + d];
    recv[(size_t)bn * D_ + d] = c * acc;
  }
}

__global__ __launch_bounds__(256) void final_kernel(
    const float* __restrict__ x2, const float* __restrict__ commit,
    const float* __restrict__ gate, const u16* __restrict__ ff,
    const float* __restrict__ fs, float* __restrict__ out) {
  long long i4 = (long long)blockIdx.x * 256 + threadIdx.x;
  long long base = i4 * 4;
  int d = (int)(base & (D_ - 1));
  int t = (int)((base >> 9) & (T_ - 1));
  int bn = (int)(base >> 18);
  float cg = commit[bn] * gate[(size_t)bn * T_ + t];
  float4 xv = *(const float4*)(x2 + base);
  ushort4 fv = *(const ushort4*)(ff + base);
  float4 sv = *(const float4*)(fs + (size_t)bn * D_ + d);
  float4 r;
  r.x = xv.x + cg * b2f(fv.x) + sv.x;
  r.y = xv.y + cg * b2f(fv.y) + sv.y;
  r.z = xv.z + cg * b2f(fv.z) + sv.z;
  r.w = xv.w + cg * b2f(fv.w) + sv.w;
  *(float4*)(out + base) = r;
}

extern "C" void kernel_launch(void* const* d_in, const int* in_sizes, int n_in,
                              void* d_out, int out_size, void* d_ws, size_t ws_size,
                              hipStream_t stream) {
  (void)in_sizes; (void)n_in; (void)out_size; (void)ws_size;
  const float* x          = (const float*)d_in[0];
  const float* gate_w     = (const float*)d_in[1];
  const float* gate_b     = (const float*)d_in[2];
  const float* ln1_g      = (const float*)d_in[3];
  const float* ln1_b      = (const float*)d_in[4];
  const float* wq         = (const float*)d_in[5];
  const float* wk         = (const float*)d_in[6];
  const float* wv         = (const float*)d_in[7];
  const float* wo         = (const float*)d_in[8];
  const float* phase      = (const float*)d_in[9];
  const float* ln2_g      = (const float*)d_in[10];
  const float* ln2_b      = (const float*)d_in[11];
  const float* up_w       = (const float*)d_in[12];
  const float* up_b       = (const float*)d_in[13];
  const float* down_w     = (const float*)d_in[14];
  const float* down_b     = (const float*)d_in[15];
  const float* commit_w   = (const float*)d_in[16];
  const float* commit_b   = (const float*)d_in[17];
  const float* center_w   = (const float*)d_in[18];
  const float* center_b   = (const float*)d_in[19];
  const float* field_in_w = (const float*)d_in[20];
  const float* field_out_w= (const float*)d_in[21];
  const float* cond       = (const float*)d_in[22];

  const long long BNTD = 8388608LL;     // 2*16*512*512
  u16* w16 = (u16*)d_ws;
  u16* R0 = w16;               // h -> attnout -> ff
  u16* R1 = w16 + BNTD;        // Q -> h2
  u16* R2 = w16 + 2 * BNTD;    // K -> up[0..)
  u16* R3 = w16 + 3 * BNTD;    // V -> up tail
  float* sm   = (float*)(w16 + 4 * BNTD);
  float* gate   = sm;
  float* cp     = sm + 16384;
  float* center = sm + 2 * 16384;
  float* hres   = sm + 3 * 16384;
  float* uu     = sm + 4 * 16384;
  float* vv     = uu + 8192;
  float* ra     = vv + 8192;
  float* recvb  = ra + 512;
  float* fsig   = recvb + 16384;
  float* commit = fsig + 16384;
  float* x2 = (float*)d_out;

  ln_gate_kernel<<<16384, 256, 0, stream>>>(x, gate_w, gate_b, ln1_g, ln1_b, gate, R0, 1);
  // fused QKV (proj encoded in blockIdx.z>>5)
  gemm_mfma_kernel<<<dim3(4, 4, 96), 256, 0, stream>>>(
      R0, wq, wk, wv, R1, R2, R3, nullptr, 512, 512, 0, nullptr, nullptr, nullptr);
  rot_gate_kernel<<<16384, 256, 0, stream>>>(R1, R2, phase, gate);
  attn_kernel<<<dim3(8, 8, 32), 256, 0, stream>>>(R1, R2, R3, R0);
  gemm_mfma_kernel<<<dim3(4, 4, 32), 256, 0, stream>>>(
      R0, wo, nullptr, nullptr, nullptr, nullptr, nullptr, x2, 512, 512, 1, nullptr, x, gate);
  ln_gate_kernel<<<16384, 256, 0, stream>>>(x2, nullptr, nullptr, ln2_g, ln2_b, nullptr, R1, 0);
  gemm_mfma_kernel<<<dim3(7, 4, 32), 256, 0, stream>>>(
      R1, up_w, nullptr, nullptr, R2, nullptr, nullptr, nullptr, 512, 828, 2, up_b, nullptr, nullptr);
  gemm_mfma_kernel<<<dim3(4, 4, 32), 256, 0, stream>>>(
      R2, down_w, nullptr, nullptr, R0, nullptr, nullptr, nullptr, 828, 512, 3, down_b, nullptr, nullptr);
  pool_kernel<<<64, 256, 0, stream>>>(x2, cp);
  commit_center_kernel<<<32, 256, 0, stream>>>(cp, commit_w, commit_b, center_w, center_b, commit, center);
  matvec_kernel<<<32, 256, 0, stream>>>(center, field_in_w, hres);
  uv_kernel<<<32, 256, 0, stream>>>(hres, uu, vv);
  racc_kernel<<<2, 256, 0, stream>>>(uu, vv, ra);
  recv_kernel<<<32, 256, 0, stream>>>(ra, commit, hres, cond, recvb);
  matvec_kernel<<<32, 256, 0, stream>>>(recvb, field_out_w, fsig);
  final_kernel<<<8192, 256, 0, stream>>>(x2, commit, gate, R0, fsig, x2);
}